// Round 1
// baseline (1462.539 us; speedup 1.0000x reference)
//
#include <hip/hip_runtime.h>
#include <hip/hip_bf16.h>

// ---------------------------------------------------------------------------
// D-MPNN molecule encoder, round 3: W-resident-in-LDS barrier-free MFMA GEMM.
//
// The 4 big GEMMs all have N=256 and K<=256 per chunk, so the whole (bf16)
// weight matrix fits in 96-128 KiB of LDS. Each block loads W ONCE
// (XOR-swizzled for conflict-free ds_read_b128), then persistently streams
// 64-row A tiles with per-lane direct global->register fragment loads
// (gather+diff fused in VALU at consume time). No __syncthreads() in the
// main loop at all -> no vmcnt(0) drains; 2-deep load pipeline hides L2/L3
// gather latency under MFMA.
//
//   step1 : buf0 = f_bonds @ W_i                    (pre-relu bf16)  [B,256]
//   iter1 : amsg=gsum(buf0); buf1=relu(buf0 + (amsg[b2a]-relu(buf0[rev]))@W_h)
//   iter2 : amsg=gsum(buf1); buf0=relu(buf0 + (amsg[b2a]-relu(buf1[rev]))@W_h)
//   final : amsg=gsum(buf0)
//   step4a: fbuf(f32) = f_atoms @ W_o[0:133]        (partials, into buf1 mem)
//   step4b: amsg = relu(fbuf + amsg @ W_o[133:] + b)   (in-place)
//   mean  : molv (bsearch over sorted atom2mol)
//   MLP   : fp32 vector GEMMs (M=4096, small)
// ---------------------------------------------------------------------------

typedef __hip_bfloat16 bf16;
typedef __attribute__((ext_vector_type(8))) short short8;
typedef __attribute__((ext_vector_type(4))) short short4v;
typedef __attribute__((ext_vector_type(4))) float f32x4;

__device__ __forceinline__ float b2f(bf16 x) { return __bfloat162float(x); }
__device__ __forceinline__ bf16  f2b(float x) { return __float2bfloat16(x); }
__device__ __forceinline__ float bs2f(short s) {
    unsigned int u = ((unsigned int)(unsigned short)s) << 16;
    float f; __builtin_memcpy(&f, &u, 4); return f;
}
__device__ __forceinline__ short f2bs(float f) {
    bf16 b = __float2bfloat16(f);
    short s; __builtin_memcpy(&s, &b, 2); return s;
}

// ---------------------------------------------------------------------------
// W-resident GEMM.  N fixed at 256.  KP in {192,256} (LDS K extent, mult 64).
// MODE: 0 = f32 rows (row stride Ktrue, W zero-padded past Ktrue)
//       1 = diff: amsg[g1[row]] - relu(msg[g2[row]])   (bf16, K=256)
//       2 = plain bf16 rows (K=256)
// ADDC: 0 none, 1 bf16 addend, 2 f32 addend (same [M,256] indexing)
// INPLACE: barrier before epilogue (out aliases the A source rows)
// ---------------------------------------------------------------------------
template <int KP, int MODE, bool RELU, bool OUTF32, int ADDC, bool INPLACE>
__global__ __launch_bounds__(256, 1) void gemm_wres(
    int M, int ntiles, int Ktrue,
    const float* __restrict__ Af,
    const bf16* __restrict__ Ab1, const bf16* __restrict__ Ab2,
    const int* __restrict__ g1, const int* __restrict__ g2,
    const bf16* __restrict__ Wt,       // [256][KP] bf16, zero-padded
    const float* __restrict__ bias,    // [256] or null
    const bf16* __restrict__ addB, const float* __restrict__ addF,
    bf16* __restrict__ outB, float* __restrict__ outF)
{
    constexpr int NK = KP / 32;
    __shared__ bf16 Wl[256 * KP];      // 96 KiB (KP=192) / 128 KiB (KP=256)

    const int t = threadIdx.x;

    // ---- one-time W load, 16B-unit XOR swizzle within each n-row ----
    {
        const int n = t;                               // 256 threads = 256 rows
        const short8* src = (const short8*)(Wt + (size_t)n * KP);
        char* dst = (char*)Wl + (size_t)n * (KP * 2);
        #pragma unroll
        for (int k16 = 0; k16 < KP / 8; k16++)
            *(short8*)(dst + ((k16 ^ (n & 7)) << 4)) = src[k16];
    }
    __syncthreads();

    const int wave = t >> 6, lane = t & 63;
    const int mrow = lane & 15;        // A row select / B col select
    const int kq   = lane >> 4;        // k-quarter within a 32-k step

    // B-fragment bases (swizzled LDS)
    const char* bbase[4];
    int bswz[4];
    #pragma unroll
    for (int tn = 0; tn < 4; tn++) {
        int n = wave * 64 + tn * 16 + mrow;
        bbase[tn] = (const char*)Wl + (size_t)n * (KP * 2);
        bswz[tn]  = (n & 7) << 4;
    }

    for (int tile = blockIdx.x; tile < ntiles; tile += gridDim.x) {
        const int bm = tile * 64;

        int  row[4]; bool rok[4];
        const bf16* pa1[4]; const bf16* pa2[4]; const float* pf[4];
        #pragma unroll
        for (int tm = 0; tm < 4; tm++) {
            row[tm] = bm + tm * 16 + mrow;
            rok[tm] = row[tm] < M;
            if (MODE == 1) {
                int r1 = rok[tm] ? g1[row[tm]] : 0;
                int r2 = rok[tm] ? g2[row[tm]] : 0;
                pa1[tm] = Ab1 + ((size_t)r1 << 8) + kq * 8;
                pa2[tm] = Ab2 + ((size_t)r2 << 8) + kq * 8;
            } else if (MODE == 2) {
                pa1[tm] = Ab1 + ((size_t)(rok[tm] ? row[tm] : 0) << 8) + kq * 8;
            } else {
                pf[tm] = Af + (size_t)(rok[tm] ? row[tm] : 0) * Ktrue + kq * 8;
            }
        }

        // issue the raw loads for kstep ks into one named slot set
        auto LOAD = [&](int ks, short8 (&u1)[4], short8 (&u2)[4], float (&uf)[4][8]) {
            #pragma unroll
            for (int tm = 0; tm < 4; tm++) {
                if (MODE == 1) {
                    if (rok[tm]) {
                        u1[tm] = *(const short8*)(pa1[tm] + ks * 32);
                        u2[tm] = *(const short8*)(pa2[tm] + ks * 32);
                    } else { u1[tm] = short8{}; u2[tm] = short8{}; }
                } else if (MODE == 2) {
                    u1[tm] = rok[tm] ? *(const short8*)(pa1[tm] + ks * 32) : short8{};
                } else {
                    const float* p = pf[tm] + ks * 32;
                    if (row[tm] < M - 1) {           // fast: next-row spill x0 weight
                        #pragma unroll
                        for (int j = 0; j < 8; j++) uf[tm][j] = p[j];
                    } else if (rok[tm]) {            // very last row: guard buffer end
                        #pragma unroll
                        for (int j = 0; j < 8; j++) {
                            int k = ks * 32 + kq * 8 + j;
                            uf[tm][j] = (k < Ktrue) ? p[j] : 0.f;
                        }
                    } else {
                        #pragma unroll
                        for (int j = 0; j < 8; j++) uf[tm][j] = 0.f;
                    }
                }
            }
        };
        // consume a slot set -> bf16 A fragments (diff/convert VALU lives here)
        auto AFRAG = [&](short8 (&u1)[4], short8 (&u2)[4], float (&uf)[4][8], short8 (&af)[4]) {
            #pragma unroll
            for (int tm = 0; tm < 4; tm++) {
                if (MODE == 1) {
                    short8 a = u1[tm], b = u2[tm], o;
                    #pragma unroll
                    for (int j = 0; j < 8; j++)
                        o[j] = f2bs(bs2f(a[j]) - fmaxf(bs2f(b[j]), 0.f));
                    af[tm] = o;
                } else if (MODE == 2) {
                    af[tm] = u1[tm];
                } else {
                    short8 o;
                    #pragma unroll
                    for (int j = 0; j < 8; j++) o[j] = f2bs(uf[tm][j]);
                    af[tm] = o;
                }
            }
        };

        f32x4 acc[4][4] = {};
        short8 a1A[4], a2A[4], a1B[4], a2B[4];
        float  fqA[4][8], fqB[4][8];

        LOAD(0, a1A, a2A, fqA);
        if (NK > 1) LOAD(1, a1B, a2B, fqB);

        #pragma unroll
        for (int ks = 0; ks < NK; ks++) {
            short8 af[4];
            if ((ks & 1) == 0) {
                AFRAG(a1A, a2A, fqA, af);
                if (ks + 2 < NK) LOAD(ks + 2, a1A, a2A, fqA);
            } else {
                AFRAG(a1B, a2B, fqB, af);
                if (ks + 2 < NK) LOAD(ks + 2, a1B, a2B, fqB);
            }
            short8 bfr[4];
            #pragma unroll
            for (int tn = 0; tn < 4; tn++)
                bfr[tn] = *(const short8*)(bbase[tn] + ((((ks * 4 + kq) << 4)) ^ bswz[tn]));
            #pragma unroll
            for (int tm = 0; tm < 4; tm++)
                #pragma unroll
                for (int tn = 0; tn < 4; tn++)
                    acc[tm][tn] = __builtin_amdgcn_mfma_f32_16x16x32_bf16(
                        af[tm], bfr[tn], acc[tm][tn], 0, 0, 0);
        }

        if (INPLACE) __syncthreads();   // all waves' A reads done before stores

        // ---- epilogue: C/D layout col=lane&15, row=(lane>>4)*4+reg ----
        #pragma unroll
        for (int tm = 0; tm < 4; tm++) {
            #pragma unroll
            for (int r = 0; r < 4; r++) {
                int orow = bm + tm * 16 + kq * 4 + r;
                if (orow >= M) continue;
                size_t rb = (size_t)orow << 8;
                #pragma unroll
                for (int tn = 0; tn < 4; tn++) {
                    int col = wave * 64 + tn * 16 + mrow;
                    float v = acc[tm][tn][r];
                    if (bias) v += bias[col];
                    if (ADDC == 1) v += b2f(addB[rb + col]);
                    else if (ADDC == 2) v += addF[rb + col];
                    if (RELU) v = fmaxf(v, 0.f);
                    if (OUTF32) outF[rb + col] = v;
                    else        outB[rb + col] = f2b(v);
                }
            }
        }
    }
}

// W[K][256] f32 (rows Koff..Koff+K) -> Wt[256][Kp] bf16, zero pad k in [K,Kp)
__global__ __launch_bounds__(256) void convert_wt(
    const float* __restrict__ W, bf16* __restrict__ Wt, int K, int Koff, int Kp)
{
    int i = blockIdx.x * 256 + threadIdx.x;
    if (i >= 256 * Kp) return;
    int n = i / Kp, k = i - n * Kp;
    Wt[i] = (k < K) ? f2b(W[(size_t)(k + Koff) * 256 + n]) : f2b(0.f);
}

// amsg[a, c4..c4+4) = sum_k relu(msg[a2b[a,k], c4..c4+4)) ; 8B vector loads
__global__ __launch_bounds__(256) void gather_sum4(
    const bf16* __restrict__ msg, const int* __restrict__ a2b,
    bf16* __restrict__ amsg, int A)
{
    int idx = blockIdx.x * 256 + threadIdx.x;
    if (idx >= A * 64) return;
    int a  = idx >> 6;
    int c4 = (idx & 63) * 4;
    const int* nb = a2b + (size_t)a * 6;
    float s0 = 0.f, s1 = 0.f, s2 = 0.f, s3 = 0.f;
    #pragma unroll
    for (int k = 0; k < 6; k++) {
        const short4v v = *(const short4v*)(msg + (size_t)nb[k] * 256 + c4);
        s0 += fmaxf(bs2f(v[0]), 0.f);
        s1 += fmaxf(bs2f(v[1]), 0.f);
        s2 += fmaxf(bs2f(v[2]), 0.f);
        s3 += fmaxf(bs2f(v[3]), 0.f);
    }
    short4v o; o[0] = f2bs(s0); o[1] = f2bs(s1); o[2] = f2bs(s2); o[3] = f2bs(s3);
    *(short4v*)(amsg + (size_t)a * 256 + c4) = o;
}

// molv[m,h] = mean over the sorted segment atom2mol==m (0 if empty)
__global__ __launch_bounds__(256) void segment_mean_kernel(
    const bf16* __restrict__ ah, const int* __restrict__ atom2mol,
    int A, float* __restrict__ molv)
{
    int m = blockIdx.x;
    int h = threadIdx.x;
    int lo = 0, hi = A;
    while (lo < hi) { int mid = (lo + hi) >> 1; if (atom2mol[mid] < m) lo = mid + 1; else hi = mid; }
    int start = lo;
    hi = A;
    while (lo < hi) { int mid = (lo + hi) >> 1; if (atom2mol[mid] <= m) lo = mid + 1; else hi = mid; }
    int end = lo;
    float s = 0.f;
    for (int a = start; a < end; a++) s += b2f(ah[(size_t)a * 256 + h]);
    float cnt = (float)(end - start);
    molv[(size_t)m * 256 + h] = s / fmaxf(cnt, 1.f);
}

// fp32 vector GEMM for the small MLP: C = relu([A1|A2] @ W + bias)
#define TM 64
#define TN 64
#define TK 16
__global__ __launch_bounds__(256) void gemm_f32(
    int M, int N, int K, int K1,
    const float* __restrict__ Af1,
    const float* __restrict__ Af2,
    const float* __restrict__ W,
    const float* __restrict__ bias,
    float* __restrict__ outF)
{
    __shared__ float As[TK][TM + 4];
    __shared__ float Bs[TK][TN + 4];
    const int bm = blockIdx.x * TM;
    const int bn = blockIdx.y * TN;
    const int t  = threadIdx.x;
    const int tx = t & 15;
    const int ty = t >> 4;
    float acc[4][4] = {};
    for (int k0 = 0; k0 < K; k0 += TK) {
        #pragma unroll
        for (int i = 0; i < 4; i++) {
            int idx = t + i * 256;
            int r = idx >> 4, kk = idx & 15;
            int rowi = bm + r, k = k0 + kk;
            float v = 0.f;
            if (rowi < M && k < K)
                v = (k < K1) ? Af1[(size_t)rowi * K1 + k]
                             : Af2[(size_t)rowi * (K - K1) + (k - K1)];
            As[kk][r] = v;
        }
        #pragma unroll
        for (int i = 0; i < 4; i++) {
            int idx = t + i * 256;
            int nn = idx & 63, kk = idx >> 6;
            int k = k0 + kk, n = bn + nn;
            float v = 0.f;
            if (k < K && n < N) v = W[(size_t)k * N + n];
            Bs[kk][nn] = v;
        }
        __syncthreads();
        #pragma unroll
        for (int kk = 0; kk < TK; kk++) {
            float a[4], b[4];
            #pragma unroll
            for (int i = 0; i < 4; i++) a[i] = As[kk][ty * 4 + i];
            #pragma unroll
            for (int j = 0; j < 4; j++) b[j] = Bs[kk][tx * 4 + j];
            #pragma unroll
            for (int i = 0; i < 4; i++)
                #pragma unroll
                for (int j = 0; j < 4; j++)
                    acc[i][j] += a[i] * b[j];
        }
        __syncthreads();
    }
    #pragma unroll
    for (int i = 0; i < 4; i++) {
        int rowi = bm + ty * 4 + i;
        if (rowi >= M) continue;
        #pragma unroll
        for (int j = 0; j < 4; j++) {
            int n = bn + tx * 4 + j;
            if (n >= N) continue;
            float v = acc[i][j] + (bias ? bias[n] : 0.f);
            outF[(size_t)rowi * N + n] = fmaxf(v, 0.f);
        }
    }
}

extern "C" void kernel_launch(void* const* d_in, const int* in_sizes, int n_in,
                              void* d_out, int out_size, void* d_ws, size_t ws_size,
                              hipStream_t stream)
{
    const float* f_atoms  = (const float*)d_in[0];
    const float* f_bonds  = (const float*)d_in[1];
    const int*   a2b      = (const int*)d_in[2];
    const int*   b2a      = (const int*)d_in[3];
    const int*   b2revb   = (const int*)d_in[4];
    const int*   atom2mol = (const int*)d_in[5];
    const float* mol_feat = (const float*)d_in[6];
    const float* W_i      = (const float*)d_in[7];
    const float* W_h      = (const float*)d_in[8];
    const float* W_o_w    = (const float*)d_in[9];
    const float* W_o_b    = (const float*)d_in[10];
    const float* W1       = (const float*)d_in[11];
    const float* b1       = (const float*)d_in[12];
    const float* W2       = (const float*)d_in[13];
    const float* b2       = (const float*)d_in[14];

    const int A  = 100000, B = 200000, H = 256;
    const int AF = 133, BF = 147;
    const int NM = 4096, MF = 200, FH = 512, EH = 256;
    const int KpS = 192;   // K extent (mult 64) for K=147 / K=133 chunks
    const int KpH = 256;

    char* ws = (char*)d_ws;
    bf16* buf0 = (bf16*)ws;  ws += (size_t)B * H * sizeof(bf16);     // 102.4 MB
    bf16* buf1 = (bf16*)ws;  ws += (size_t)B * H * sizeof(bf16);     // 102.4 MB (also f32 [A,256] partials)
    bf16* amsg = (bf16*)ws;  ws += (size_t)A * H * sizeof(bf16);     //  51.2 MB (also final atom_hiddens)
    float* molv = (float*)ws; ws += (size_t)NM * H * sizeof(float);  //   4 MB
    float* hbuf = (float*)ws; ws += (size_t)NM * FH * sizeof(float); //   8 MB
    bf16* WtI  = (bf16*)ws;  ws += (size_t)256 * KpS * sizeof(bf16);
    bf16* WtH  = (bf16*)ws;  ws += (size_t)256 * KpH * sizeof(bf16);
    bf16* WtO1 = (bf16*)ws;  ws += (size_t)256 * KpS * sizeof(bf16);
    bf16* WtO2 = (bf16*)ws;  ws += (size_t)256 * KpH * sizeof(bf16);
    float* fbuf = (float*)buf1;   // step4a f32 partials: A*256*4 == B*256*2 bytes

    dim3 blk(256);
    const int G = 256;                        // 1 persistent block per CU
    const int ntB = (B + 63) / 64;            // 3125 (exact)
    const int ntA = (A + 63) / 64;            // 1563 (last tile partial)
    const int gsG = (A * 64 + 255) / 256;

    // 0. weights -> bf16 [256][Kp] (k-contiguous, zero-padded)
    convert_wt<<<dim3((256 * KpS + 255) / 256), blk, 0, stream>>>(W_i,   WtI,  BF,  0,   KpS);
    convert_wt<<<dim3((256 * KpH + 255) / 256), blk, 0, stream>>>(W_h,   WtH,  H,   0,   KpH);
    convert_wt<<<dim3((256 * KpS + 255) / 256), blk, 0, stream>>>(W_o_w, WtO1, AF,  0,   KpS);
    convert_wt<<<dim3((256 * KpH + 255) / 256), blk, 0, stream>>>(W_o_w, WtO2, H,   AF,  KpH);

    // 1. buf0 = f_bonds @ W_i  (pre-relu)
    gemm_wres<192, 0, false, false, 0, false><<<dim3(G), blk, 0, stream>>>(
        B, ntB, BF, f_bonds, nullptr, nullptr, nullptr, nullptr,
        WtI, nullptr, nullptr, nullptr, buf0, nullptr);

    // 2a. iter 1
    gather_sum4<<<dim3(gsG), blk, 0, stream>>>(buf0, a2b, amsg, A);
    gemm_wres<256, 1, true, false, 1, false><<<dim3(G), blk, 0, stream>>>(
        B, ntB, H, nullptr, amsg, buf0, b2a, b2revb,
        WtH, nullptr, buf0, nullptr, buf1, nullptr);

    // 2b. iter 2 (in-place into buf0; addC read same-thread pre-write)
    gather_sum4<<<dim3(gsG), blk, 0, stream>>>(buf1, a2b, amsg, A);
    gemm_wres<256, 1, true, false, 1, false><<<dim3(G), blk, 0, stream>>>(
        B, ntB, H, nullptr, amsg, buf1, b2a, b2revb,
        WtH, nullptr, buf0, nullptr, buf0, nullptr);

    // 3. final neighbor sum
    gather_sum4<<<dim3(gsG), blk, 0, stream>>>(buf0, a2b, amsg, A);

    // 4a. fbuf = f_atoms @ W_o[0:133]  (f32 partials)
    gemm_wres<192, 0, false, true, 0, false><<<dim3(G), blk, 0, stream>>>(
        A, ntA, AF, f_atoms, nullptr, nullptr, nullptr, nullptr,
        WtO1, nullptr, nullptr, nullptr, nullptr, fbuf);

    // 4b. amsg = relu(fbuf + amsg @ W_o[133:] + b)   (in-place over amsg)
    gemm_wres<256, 2, true, false, 2, true><<<dim3(G), blk, 0, stream>>>(
        A, ntA, H, nullptr, amsg, nullptr, nullptr, nullptr,
        WtO2, W_o_b, nullptr, fbuf, amsg, nullptr);

    // 5. per-molecule mean
    segment_mean_kernel<<<dim3(NM), blk, 0, stream>>>(amsg, atom2mol, A, molv);

    // 6. hbuf = relu([molv | mol_feat] @ W1 + b1)
    gemm_f32<<<dim3((NM + TM - 1) / TM, FH / TN), blk, 0, stream>>>(
        NM, FH, H + MF, H, molv, mol_feat, W1, b1, hbuf);

    // 7. out = relu(hbuf @ W2 + b2)
    gemm_f32<<<dim3((NM + TM - 1) / TM, EH / TN), blk, 0, stream>>>(
        NM, EH, FH, FH, hbuf, nullptr, W2, b2, (float*)d_out);
}

// Round 2
// 824.452 us; speedup vs baseline: 1.7740x; 1.7740x over previous
//
#include <hip/hip_runtime.h>
#include <hip/hip_bf16.h>

// ---------------------------------------------------------------------------
// D-MPNN molecule encoder, round 4: W-resident LDS + burst-staged A tiles.
//
// Round-3 failure mode (measured): 1 wave/SIMD + 2-step register pipeline =>
// ~2 KB outstanding loads per CU vs ~20 KB needed for BW-bound operation,
// plus 4x duplicated A loads across waves. Fix: cooperative 32-row full-K
// A tile in LDS (each row loaded once), whole next-tile load burst (48 KB)
// issued at compute start so it spans the tile's compute+epilogue.
//
//   step1 : buf0 = f_bonds @ W_i                    (pre-relu bf16)  [B,256]
//   iter1 : amsg=gsum(buf0); buf1=relu(buf0 + (amsg[b2a]-relu(buf0[rev]))@W_h)
//   iter2 : amsg=gsum(buf1); buf0=relu(buf0 + (amsg[b2a]-relu(buf1[rev]))@W_h)
//   final : amsg=gsum(buf0)
//   step4a: fbuf(f32) = f_atoms @ W_o[0:133]        (partials, in buf1 mem)
//   step4b: amsg = relu(fbuf + amsg @ W_o[133:] + b)   (in-place)
//   mean  : molv (bsearch over sorted atom2mol)
//   MLP   : fp32 vector GEMMs (M=4096, small)
// ---------------------------------------------------------------------------

typedef __hip_bfloat16 bf16;
typedef __attribute__((ext_vector_type(8))) short short8;
typedef __attribute__((ext_vector_type(4))) short short4v;
typedef __attribute__((ext_vector_type(4))) float f32x4;
typedef __attribute__((ext_vector_type(4), aligned(4))) float f32x4u;

__device__ __forceinline__ float b2f(bf16 x) { return __bfloat162float(x); }
__device__ __forceinline__ bf16  f2b(float x) { return __float2bfloat16(x); }
__device__ __forceinline__ float bs2f(short s) {
    unsigned int u = ((unsigned int)(unsigned short)s) << 16;
    float f; __builtin_memcpy(&f, &u, 4); return f;
}
__device__ __forceinline__ short f2bs(float f) {
    bf16 b = __float2bfloat16(f);
    short s; __builtin_memcpy(&s, &b, 2); return s;
}

#define GRID 256
#define TR 32   // tile rows; 200000%32==0 and 100000%32==0 -> no partial tiles

// ---------------------------------------------------------------------------
// W-resident GEMM. N fixed 256. KP in {192,256}.
// MODE: 0 = f32 rows (stride Ktrue, garbage past Ktrue ok: W zero-padded)
//       1 = diff: amsg[g1[row]] - relu(msg[g2[row]])   (bf16, K=256)
//       2 = plain bf16 rows (K=256)
// ADDC: 0 none, 1 bf16 tile via LDS roundtrip, 2 f32 read direct in epilogue
// ---------------------------------------------------------------------------
template <int KP, int MODE, bool RELU, int ADDC, bool HASBIAS, bool OUTF32>
__global__ __launch_bounds__(512, 1) void gemm_wres(
    int M, int ntiles, int Ktrue,
    const float* __restrict__ Af,
    const bf16* __restrict__ Ab1, const bf16* __restrict__ Ab2,
    const int* __restrict__ g1, const int* __restrict__ g2,
    const bf16* __restrict__ Wt,       // [256][KP] bf16 zero-padded
    const float* __restrict__ bias,    // [256] or null
    const bf16* __restrict__ addB, const float* __restrict__ addF,
    bf16* __restrict__ outB, float* __restrict__ outF)
{
    constexpr int NK  = KP / 32;   // K-steps
    constexpr int NU  = KP / 8;    // 16B units per row
    constexpr int KP2 = KP * 2;    // LDS row stride (bytes)
    __shared__ bf16 Wl[256 * KP];  // 96 KiB (KP=192) / 128 KiB (KP=256)
    __shared__ bf16 At[TR * KP];   // 12 KiB / 16 KiB

    const int t = threadIdx.x;
    int tile = blockIdx.x;
    if (tile >= ntiles) return;    // block-uniform

    // ---- one-time W load, 16B-unit XOR swizzle within each n-row ----
    {
        int n = t >> 1, half = t & 1;
        const short8* src = (const short8*)(Wt + (size_t)n * KP) + half * (NU / 2);
        char* dst = (char*)Wl + (size_t)n * KP2;
        #pragma unroll
        for (int i = 0; i < NU / 2; i++) {
            int g = half * (NU / 2) + i;
            *(short8*)(dst + ((g ^ (n & 7)) << 4)) = src[i];
        }
    }
    __syncthreads();

    const int wave = t >> 6, lane = t & 63;
    const int mrow = lane & 15, kq = lane >> 4;
    const int r = t >> 4, j = t & 15;        // staging: 16 threads per row

    float biasReg[2] = {0.f, 0.f};
    if (HASBIAS) {
        #pragma unroll
        for (int tn = 0; tn < 2; tn++)
            biasReg[tn] = bias[wave * 32 + tn * 16 + mrow];
    }

    // prefetch register sets (static indexing only)
    short8 pA[2], pB[2];   // MODE 1/2 raw rows (32 B per source per thread)
    f32x4  pF[3];          // MODE 0 f32 chunks
    short8 pC[2];          // ADDC==1 bf16 addend

    auto prefA = [&](int tl) {
        int row = tl * TR + r;
        if (MODE == 1) {
            int r1 = g1[row], r2 = g2[row];
            const char* s1 = (const char*)(Ab1 + ((size_t)r1 << 8));
            const char* s2 = (const char*)(Ab2 + ((size_t)r2 << 8));
            #pragma unroll
            for (int u = 0; u < 2; u++) {
                pA[u] = *(const short8*)(s1 + ((j + 16 * u) << 4));
                pB[u] = *(const short8*)(s2 + ((j + 16 * u) << 4));
            }
        } else if (MODE == 2) {
            const char* s1 = (const char*)(Ab1 + ((size_t)row << 8));
            #pragma unroll
            for (int u = 0; u < 2; u++)
                pA[u] = *(const short8*)(s1 + ((j + 16 * u) << 4));
        } else {
            const float* src = Af + (size_t)row * Ktrue;
            #pragma unroll
            for (int v = 0; v < 3; v++) {
                int c = j + 16 * v;                 // f32 16B-chunk index, 0..47
                f32x4 val = {0.f, 0.f, 0.f, 0.f};
                if (c * 4 < Ktrue) {
                    if (row == M - 1 && c * 4 + 4 > Ktrue) {
                        #pragma unroll
                        for (int e = 0; e < 4; e++)
                            if (c * 4 + e < Ktrue) val[e] = src[c * 4 + e];
                    } else {
                        val = *(const f32x4u*)(src + c * 4);  // may read next row: safe, W-padded
                    }
                }
                pF[v] = val;
            }
        }
    };
    auto prefAdd = [&](int tl) {
        int row = tl * TR + r;
        const char* s = (const char*)(addB + ((size_t)row << 8));
        #pragma unroll
        for (int u = 0; u < 2; u++)
            pC[u] = *(const short8*)(s + ((j + 16 * u) << 4));
    };
    auto convWrite = [&]() {
        char* dst = (char*)At + (size_t)r * KP2;
        if (MODE == 1) {
            #pragma unroll
            for (int u = 0; u < 2; u++) {
                short8 a = pA[u], b = pB[u], o;
                #pragma unroll
                for (int e = 0; e < 8; e++)
                    o[e] = f2bs(bs2f(a[e]) - fmaxf(bs2f(b[e]), 0.f));
                int g = j + 16 * u;
                *(short8*)(dst + ((g ^ (r & 7)) << 4)) = o;
            }
        } else if (MODE == 2) {
            #pragma unroll
            for (int u = 0; u < 2; u++) {
                int g = j + 16 * u;
                *(short8*)(dst + ((g ^ (r & 7)) << 4)) = pA[u];
            }
        } else {
            #pragma unroll
            for (int v = 0; v < 3; v++) {
                int c = j + 16 * v;
                f32x4 x = pF[v];
                short4v o;
                #pragma unroll
                for (int e = 0; e < 4; e++) o[e] = f2bs(x[e]);
                int unit = c >> 1, sub = (c & 1) << 3;
                *(short4v*)(dst + ((unit ^ (r & 7)) << 4) + sub) = o;
            }
        }
    };

    prefA(tile);
    for (;;) {
        convWrite();
        __syncthreads();                      // b1: A tile ready
        const int nxt = tile + GRID;
        const bool more = nxt < ntiles;
        if (ADDC == 1) prefAdd(tile);         // oldest in vmcnt queue
        if (more) prefA(nxt);                 // burst spans compute+epilogue

        f32x4 acc[2][2] = {};
        #pragma unroll
        for (int ks = 0; ks < NK; ks++) {
            short8 afr[2], bfr[2];
            #pragma unroll
            for (int tm = 0; tm < 2; tm++) {
                int arow = tm * 16 + mrow;
                afr[tm] = *(const short8*)((char*)At + (size_t)arow * KP2 +
                            (((ks * 4 + kq) ^ (arow & 7)) << 4));
            }
            #pragma unroll
            for (int tn = 0; tn < 2; tn++) {
                int n = wave * 32 + tn * 16 + mrow;
                bfr[tn] = *(const short8*)((char*)Wl + (size_t)n * KP2 +
                            (((ks * 4 + kq) ^ (n & 7)) << 4));
            }
            #pragma unroll
            for (int tm = 0; tm < 2; tm++)
                #pragma unroll
                for (int tn = 0; tn < 2; tn++)
                    acc[tm][tn] = __builtin_amdgcn_mfma_f32_16x16x32_bf16(
                        afr[tm], bfr[tn], acc[tm][tn], 0, 0, 0);
        }
        __syncthreads();                      // b2: all A-LDS reads done

        if (ADDC == 1) {                      // roundtrip addend through At
            char* dst = (char*)At + (size_t)r * KP2;
            #pragma unroll
            for (int u = 0; u < 2; u++) {
                int g = j + 16 * u;
                *(short8*)(dst + ((g ^ (r & 7)) << 4)) = pC[u];
            }
            __syncthreads();                  // b3: addend tile ready
        }

        const int bm = tile * TR;
        #pragma unroll
        for (int tm = 0; tm < 2; tm++) {
            #pragma unroll
            for (int rr = 0; rr < 4; rr++) {
                int lrow = tm * 16 + kq * 4 + rr;
                size_t rb = (size_t)(bm + lrow) << 8;
                #pragma unroll
                for (int tn = 0; tn < 2; tn++) {
                    int col = wave * 32 + tn * 16 + mrow;
                    float v = acc[tm][tn][rr];
                    if (HASBIAS) v += biasReg[tn];
                    if (ADDC == 1) {
                        int u = col >> 3;
                        short s = *(const short*)((char*)At + (size_t)lrow * KP2 +
                                   ((u ^ (lrow & 7)) << 4) + ((col & 7) << 1));
                        v += bs2f(s);
                    } else if (ADDC == 2) {
                        v += addF[rb + col];
                    }
                    if (RELU) v = fmaxf(v, 0.f);
                    if (OUTF32) outF[rb + col] = v;
                    else        outB[rb + col] = f2b(v);
                }
            }
        }
        if (!more) break;
        if (ADDC == 1) __syncthreads();       // b4: epilogue LDS reads done
        tile = nxt;
    }
}

// W[K][256] f32 (rows Koff..Koff+K) -> Wt[256][Kp] bf16, zero pad k in [K,Kp)
__global__ __launch_bounds__(256) void convert_wt(
    const float* __restrict__ W, bf16* __restrict__ Wt, int K, int Koff, int Kp)
{
    int i = blockIdx.x * 256 + threadIdx.x;
    if (i >= 256 * Kp) return;
    int n = i / Kp, k = i - n * Kp;
    Wt[i] = (k < K) ? f2b(W[(size_t)(k + Koff) * 256 + n]) : f2b(0.f);
}

// amsg[a, c4..c4+4) = sum_k relu(msg[a2b[a,k], c4..c4+4)) ; 8B vector loads
__global__ __launch_bounds__(256) void gather_sum4(
    const bf16* __restrict__ msg, const int* __restrict__ a2b,
    bf16* __restrict__ amsg, int A)
{
    int idx = blockIdx.x * 256 + threadIdx.x;
    if (idx >= A * 64) return;
    int a  = idx >> 6;
    int c4 = (idx & 63) * 4;
    const int* nb = a2b + (size_t)a * 6;
    float s0 = 0.f, s1 = 0.f, s2 = 0.f, s3 = 0.f;
    #pragma unroll
    for (int k = 0; k < 6; k++) {
        const short4v v = *(const short4v*)(msg + (size_t)nb[k] * 256 + c4);
        s0 += fmaxf(bs2f(v[0]), 0.f);
        s1 += fmaxf(bs2f(v[1]), 0.f);
        s2 += fmaxf(bs2f(v[2]), 0.f);
        s3 += fmaxf(bs2f(v[3]), 0.f);
    }
    short4v o; o[0] = f2bs(s0); o[1] = f2bs(s1); o[2] = f2bs(s2); o[3] = f2bs(s3);
    *(short4v*)(amsg + (size_t)a * 256 + c4) = o;
}

// molv[m,h] = mean over the sorted segment atom2mol==m (0 if empty)
__global__ __launch_bounds__(256) void segment_mean_kernel(
    const bf16* __restrict__ ah, const int* __restrict__ atom2mol,
    int A, float* __restrict__ molv)
{
    int m = blockIdx.x;
    int h = threadIdx.x;
    int lo = 0, hi = A;
    while (lo < hi) { int mid = (lo + hi) >> 1; if (atom2mol[mid] < m) lo = mid + 1; else hi = mid; }
    int start = lo;
    hi = A;
    while (lo < hi) { int mid = (lo + hi) >> 1; if (atom2mol[mid] <= m) lo = mid + 1; else hi = mid; }
    int end = lo;
    float s = 0.f;
    for (int a = start; a < end; a++) s += b2f(ah[(size_t)a * 256 + h]);
    float cnt = (float)(end - start);
    molv[(size_t)m * 256 + h] = s / fmaxf(cnt, 1.f);
}

// fp32 vector GEMM for the small MLP: C = relu([A1|A2] @ W + bias)
#define TM 64
#define TN 64
#define TK 16
__global__ __launch_bounds__(256) void gemm_f32(
    int M, int N, int K, int K1,
    const float* __restrict__ Af1,
    const float* __restrict__ Af2,
    const float* __restrict__ W,
    const float* __restrict__ bias,
    float* __restrict__ outF)
{
    __shared__ float As[TK][TM + 4];
    __shared__ float Bs[TK][TN + 4];
    const int bm = blockIdx.x * TM;
    const int bn = blockIdx.y * TN;
    const int t  = threadIdx.x;
    const int tx = t & 15;
    const int ty = t >> 4;
    float acc[4][4] = {};
    for (int k0 = 0; k0 < K; k0 += TK) {
        #pragma unroll
        for (int i = 0; i < 4; i++) {
            int idx = t + i * 256;
            int rr = idx >> 4, kk = idx & 15;
            int rowi = bm + rr, k = k0 + kk;
            float v = 0.f;
            if (rowi < M && k < K)
                v = (k < K1) ? Af1[(size_t)rowi * K1 + k]
                             : Af2[(size_t)rowi * (K - K1) + (k - K1)];
            As[kk][rr] = v;
        }
        #pragma unroll
        for (int i = 0; i < 4; i++) {
            int idx = t + i * 256;
            int nn = idx & 63, kk = idx >> 6;
            int k = k0 + kk, n = bn + nn;
            float v = 0.f;
            if (k < K && n < N) v = W[(size_t)k * N + n];
            Bs[kk][nn] = v;
        }
        __syncthreads();
        #pragma unroll
        for (int kk = 0; kk < TK; kk++) {
            float a[4], b[4];
            #pragma unroll
            for (int i = 0; i < 4; i++) a[i] = As[kk][ty * 4 + i];
            #pragma unroll
            for (int jj = 0; jj < 4; jj++) b[jj] = Bs[kk][tx * 4 + jj];
            #pragma unroll
            for (int i = 0; i < 4; i++)
                #pragma unroll
                for (int jj = 0; jj < 4; jj++)
                    acc[i][jj] += a[i] * b[jj];
        }
        __syncthreads();
    }
    #pragma unroll
    for (int i = 0; i < 4; i++) {
        int rowi = bm + ty * 4 + i;
        if (rowi >= M) continue;
        #pragma unroll
        for (int jj = 0; jj < 4; jj++) {
            int n = bn + tx * 4 + jj;
            if (n >= N) continue;
            float v = acc[i][jj] + (bias ? bias[n] : 0.f);
            outF[(size_t)rowi * N + n] = fmaxf(v, 0.f);
        }
    }
}

extern "C" void kernel_launch(void* const* d_in, const int* in_sizes, int n_in,
                              void* d_out, int out_size, void* d_ws, size_t ws_size,
                              hipStream_t stream)
{
    const float* f_atoms  = (const float*)d_in[0];
    const float* f_bonds  = (const float*)d_in[1];
    const int*   a2b      = (const int*)d_in[2];
    const int*   b2a      = (const int*)d_in[3];
    const int*   b2revb   = (const int*)d_in[4];
    const int*   atom2mol = (const int*)d_in[5];
    const float* mol_feat = (const float*)d_in[6];
    const float* W_i      = (const float*)d_in[7];
    const float* W_h      = (const float*)d_in[8];
    const float* W_o_w    = (const float*)d_in[9];
    const float* W_o_b    = (const float*)d_in[10];
    const float* W1       = (const float*)d_in[11];
    const float* b1       = (const float*)d_in[12];
    const float* W2       = (const float*)d_in[13];
    const float* b2       = (const float*)d_in[14];

    const int A  = 100000, B = 200000, H = 256;
    const int AF = 133, BF = 147;
    const int NM = 4096, MF = 200, FH = 512, EH = 256;
    const int KpS = 192;
    const int KpH = 256;

    char* ws = (char*)d_ws;
    bf16* buf0 = (bf16*)ws;  ws += (size_t)B * H * sizeof(bf16);     // 102.4 MB
    bf16* buf1 = (bf16*)ws;  ws += (size_t)B * H * sizeof(bf16);     // 102.4 MB (also f32 [A,256] fbuf)
    bf16* amsg = (bf16*)ws;  ws += (size_t)A * H * sizeof(bf16);     //  51.2 MB (also atom_hiddens)
    float* molv = (float*)ws; ws += (size_t)NM * H * sizeof(float);  //   4 MB
    float* hbuf = (float*)ws; ws += (size_t)NM * FH * sizeof(float); //   8 MB
    bf16* WtI  = (bf16*)ws;  ws += (size_t)256 * KpS * sizeof(bf16);
    bf16* WtH  = (bf16*)ws;  ws += (size_t)256 * KpH * sizeof(bf16);
    bf16* WtO1 = (bf16*)ws;  ws += (size_t)256 * KpS * sizeof(bf16);
    bf16* WtO2 = (bf16*)ws;  ws += (size_t)256 * KpH * sizeof(bf16);
    float* fbuf = (float*)buf1;   // A*256*4 B == B*256*2 B exactly

    dim3 blk(256), blkG(512);
    const int ntB = B / TR;                   // 6250
    const int ntA = A / TR;                   // 3125
    const int gsG = (A * 64 + 255) / 256;

    // 0. weights -> bf16 [256][Kp] (k-contiguous, zero-padded)
    convert_wt<<<dim3((256 * KpS + 255) / 256), blk, 0, stream>>>(W_i,   WtI,  BF,  0,  KpS);
    convert_wt<<<dim3((256 * KpH + 255) / 256), blk, 0, stream>>>(W_h,   WtH,  H,   0,  KpH);
    convert_wt<<<dim3((256 * KpS + 255) / 256), blk, 0, stream>>>(W_o_w, WtO1, AF,  0,  KpS);
    convert_wt<<<dim3((256 * KpH + 255) / 256), blk, 0, stream>>>(W_o_w, WtO2, H,   AF, KpH);

    // 1. buf0 = f_bonds @ W_i  (pre-relu)
    gemm_wres<192, 0, false, 0, false, false><<<dim3(GRID), blkG, 0, stream>>>(
        B, ntB, BF, f_bonds, nullptr, nullptr, nullptr, nullptr,
        WtI, nullptr, nullptr, nullptr, buf0, nullptr);

    // 2a. iter 1
    gather_sum4<<<dim3(gsG), blk, 0, stream>>>(buf0, a2b, amsg, A);
    gemm_wres<256, 1, true, 1, false, false><<<dim3(GRID), blkG, 0, stream>>>(
        B, ntB, H, nullptr, amsg, buf0, b2a, b2revb,
        WtH, nullptr, buf0, nullptr, buf1, nullptr);

    // 2b. iter 2 (in-place into buf0; addC rows prefetched before stores)
    gather_sum4<<<dim3(gsG), blk, 0, stream>>>(buf1, a2b, amsg, A);
    gemm_wres<256, 1, true, 1, false, false><<<dim3(GRID), blkG, 0, stream>>>(
        B, ntB, H, nullptr, amsg, buf1, b2a, b2revb,
        WtH, nullptr, buf0, nullptr, buf0, nullptr);

    // 3. final neighbor sum
    gather_sum4<<<dim3(gsG), blk, 0, stream>>>(buf0, a2b, amsg, A);

    // 4a. fbuf = f_atoms @ W_o[0:133]  (f32 partials)
    gemm_wres<192, 0, false, 0, false, true><<<dim3(GRID), blkG, 0, stream>>>(
        A, ntA, AF, f_atoms, nullptr, nullptr, nullptr, nullptr,
        WtO1, nullptr, nullptr, nullptr, nullptr, fbuf);

    // 4b. amsg = relu(fbuf + amsg @ W_o[133:] + b)   (in-place over amsg)
    gemm_wres<256, 2, true, 2, true, false><<<dim3(GRID), blkG, 0, stream>>>(
        A, ntA, H, nullptr, amsg, nullptr, nullptr, nullptr,
        WtO2, W_o_b, nullptr, fbuf, amsg, nullptr);

    // 5. per-molecule mean
    segment_mean_kernel<<<dim3(NM), blk, 0, stream>>>(amsg, atom2mol, A, molv);

    // 6. hbuf = relu([molv | mol_feat] @ W1 + b1)
    gemm_f32<<<dim3((NM + TM - 1) / TM, FH / TN), blk, 0, stream>>>(
        NM, FH, H + MF, H, molv, mol_feat, W1, b1, hbuf);

    // 7. out = relu(hbuf @ W2 + b2)
    gemm_f32<<<dim3((NM + TM - 1) / TM, EH / TN), blk, 0, stream>>>(
        NM, EH, FH, FH, hbuf, nullptr, W2, b2, (float*)d_out);
}

// Round 3
// 696.698 us; speedup vs baseline: 2.0992x; 1.1834x over previous
//
#include <hip/hip_runtime.h>
#include <hip/hip_bf16.h>

// ---------------------------------------------------------------------------
// D-MPNN molecule encoder, round 5: MLP moved to MFMA via bf16 hi/lo split.
//
// Big path (unchanged from round 4, measured good): W-resident LDS GEMMs with
// burst-staged 32-row A tiles.
//
// MLP path (new): x = xh + xl (bf16 hi + bf16 remainder). Expanded operands
//   A' = [Ah | Al | Ah],  W' = [Wh | Wh | Wl]   (K3 = 3*512 = 1536)
// so a PLAIN bf16 GEMM over K3 computes Ah.Wh + Al.Wh + Ah.Wl = fp32-accurate
// (dropped Al.Wl ~ 2^-16 rel). Both MLP GEMMs share K3=1536.
//   segment_mean3 -> A1' planes (molv),  conv_feat -> A1' planes (mol_feat)
//   gemm3<OUT3=1>: A2' = relu(A1' @ W1' + b1)  (epilogue emits hi/lo planes)
//   gemm3<OUT3=0>: out = relu(A2' @ W2' + b2)  (f32)
// A1'/A2' overlay buf0 (free after step 3).
// ---------------------------------------------------------------------------

typedef __hip_bfloat16 bf16;
typedef __attribute__((ext_vector_type(8))) short short8;
typedef __attribute__((ext_vector_type(4))) short short4v;
typedef __attribute__((ext_vector_type(4))) float f32x4;
typedef __attribute__((ext_vector_type(4), aligned(4))) float f32x4u;

__device__ __forceinline__ float b2f(bf16 x) { return __bfloat162float(x); }
__device__ __forceinline__ bf16  f2b(float x) { return __float2bfloat16(x); }
__device__ __forceinline__ float bs2f(short s) {
    unsigned int u = ((unsigned int)(unsigned short)s) << 16;
    float f; __builtin_memcpy(&f, &u, 4); return f;
}
__device__ __forceinline__ short f2bs(float f) {
    bf16 b = __float2bfloat16(f);
    short s; __builtin_memcpy(&s, &b, 2); return s;
}

#define GRID 256
#define TR 32   // tile rows; 200000%32==0 and 100000%32==0 -> no partial tiles

// ---------------------------------------------------------------------------
// W-resident GEMM. N fixed 256. KP in {192,256}.  (round-4, proven)
// MODE: 0 = f32 rows; 1 = diff amsg[g1]-relu(msg[g2]); 2 = plain bf16 rows
// ADDC: 0 none, 1 bf16 tile via LDS roundtrip, 2 f32 read direct in epilogue
// ---------------------------------------------------------------------------
template <int KP, int MODE, bool RELU, int ADDC, bool HASBIAS, bool OUTF32>
__global__ __launch_bounds__(512, 1) void gemm_wres(
    int M, int ntiles, int Ktrue,
    const float* __restrict__ Af,
    const bf16* __restrict__ Ab1, const bf16* __restrict__ Ab2,
    const int* __restrict__ g1, const int* __restrict__ g2,
    const bf16* __restrict__ Wt,       // [256][KP] bf16 zero-padded
    const float* __restrict__ bias,    // [256] or null
    const bf16* __restrict__ addB, const float* __restrict__ addF,
    bf16* __restrict__ outB, float* __restrict__ outF)
{
    constexpr int NK  = KP / 32;
    constexpr int NU  = KP / 8;
    constexpr int KP2 = KP * 2;
    __shared__ bf16 Wl[256 * KP];
    __shared__ bf16 At[TR * KP];

    const int t = threadIdx.x;
    int tile = blockIdx.x;
    if (tile >= ntiles) return;

    {
        int n = t >> 1, half = t & 1;
        const short8* src = (const short8*)(Wt + (size_t)n * KP) + half * (NU / 2);
        char* dst = (char*)Wl + (size_t)n * KP2;
        #pragma unroll
        for (int i = 0; i < NU / 2; i++) {
            int g = half * (NU / 2) + i;
            *(short8*)(dst + ((g ^ (n & 7)) << 4)) = src[i];
        }
    }
    __syncthreads();

    const int wave = t >> 6, lane = t & 63;
    const int mrow = lane & 15, kq = lane >> 4;
    const int r = t >> 4, j = t & 15;

    float biasReg[2] = {0.f, 0.f};
    if (HASBIAS) {
        #pragma unroll
        for (int tn = 0; tn < 2; tn++)
            biasReg[tn] = bias[wave * 32 + tn * 16 + mrow];
    }

    short8 pA[2], pB[2];
    f32x4  pF[3];
    short8 pC[2];

    auto prefA = [&](int tl) {
        int row = tl * TR + r;
        if (MODE == 1) {
            int r1 = g1[row], r2 = g2[row];
            const char* s1 = (const char*)(Ab1 + ((size_t)r1 << 8));
            const char* s2 = (const char*)(Ab2 + ((size_t)r2 << 8));
            #pragma unroll
            for (int u = 0; u < 2; u++) {
                pA[u] = *(const short8*)(s1 + ((j + 16 * u) << 4));
                pB[u] = *(const short8*)(s2 + ((j + 16 * u) << 4));
            }
        } else if (MODE == 2) {
            const char* s1 = (const char*)(Ab1 + ((size_t)row << 8));
            #pragma unroll
            for (int u = 0; u < 2; u++)
                pA[u] = *(const short8*)(s1 + ((j + 16 * u) << 4));
        } else {
            const float* src = Af + (size_t)row * Ktrue;
            #pragma unroll
            for (int v = 0; v < 3; v++) {
                int c = j + 16 * v;
                f32x4 val = {0.f, 0.f, 0.f, 0.f};
                if (c * 4 < Ktrue) {
                    if (row == M - 1 && c * 4 + 4 > Ktrue) {
                        #pragma unroll
                        for (int e = 0; e < 4; e++)
                            if (c * 4 + e < Ktrue) val[e] = src[c * 4 + e];
                    } else {
                        val = *(const f32x4u*)(src + c * 4);
                    }
                }
                pF[v] = val;
            }
        }
    };
    auto prefAdd = [&](int tl) {
        int row = tl * TR + r;
        const char* s = (const char*)(addB + ((size_t)row << 8));
        #pragma unroll
        for (int u = 0; u < 2; u++)
            pC[u] = *(const short8*)(s + ((j + 16 * u) << 4));
    };
    auto convWrite = [&]() {
        char* dst = (char*)At + (size_t)r * KP2;
        if (MODE == 1) {
            #pragma unroll
            for (int u = 0; u < 2; u++) {
                short8 a = pA[u], b = pB[u], o;
                #pragma unroll
                for (int e = 0; e < 8; e++)
                    o[e] = f2bs(bs2f(a[e]) - fmaxf(bs2f(b[e]), 0.f));
                int g = j + 16 * u;
                *(short8*)(dst + ((g ^ (r & 7)) << 4)) = o;
            }
        } else if (MODE == 2) {
            #pragma unroll
            for (int u = 0; u < 2; u++) {
                int g = j + 16 * u;
                *(short8*)(dst + ((g ^ (r & 7)) << 4)) = pA[u];
            }
        } else {
            #pragma unroll
            for (int v = 0; v < 3; v++) {
                int c = j + 16 * v;
                f32x4 x = pF[v];
                short4v o;
                #pragma unroll
                for (int e = 0; e < 4; e++) o[e] = f2bs(x[e]);
                int unit = c >> 1, sub = (c & 1) << 3;
                *(short4v*)(dst + ((unit ^ (r & 7)) << 4) + sub) = o;
            }
        }
    };

    prefA(tile);
    for (;;) {
        convWrite();
        __syncthreads();                      // b1: A tile ready
        const int nxt = tile + GRID;
        const bool more = nxt < ntiles;
        if (ADDC == 1) prefAdd(tile);
        if (more) prefA(nxt);

        f32x4 acc[2][2] = {};
        #pragma unroll
        for (int ks = 0; ks < NK; ks++) {
            short8 afr[2], bfr[2];
            #pragma unroll
            for (int tm = 0; tm < 2; tm++) {
                int arow = tm * 16 + mrow;
                afr[tm] = *(const short8*)((char*)At + (size_t)arow * KP2 +
                            (((ks * 4 + kq) ^ (arow & 7)) << 4));
            }
            #pragma unroll
            for (int tn = 0; tn < 2; tn++) {
                int n = wave * 32 + tn * 16 + mrow;
                bfr[tn] = *(const short8*)((char*)Wl + (size_t)n * KP2 +
                            (((ks * 4 + kq) ^ (n & 7)) << 4));
            }
            #pragma unroll
            for (int tm = 0; tm < 2; tm++)
                #pragma unroll
                for (int tn = 0; tn < 2; tn++)
                    acc[tm][tn] = __builtin_amdgcn_mfma_f32_16x16x32_bf16(
                        afr[tm], bfr[tn], acc[tm][tn], 0, 0, 0);
        }
        __syncthreads();                      // b2: all A-LDS reads done

        if (ADDC == 1) {
            char* dst = (char*)At + (size_t)r * KP2;
            #pragma unroll
            for (int u = 0; u < 2; u++) {
                int g = j + 16 * u;
                *(short8*)(dst + ((g ^ (r & 7)) << 4)) = pC[u];
            }
            __syncthreads();                  // b3: addend tile ready
        }

        const int bm = tile * TR;
        #pragma unroll
        for (int tm = 0; tm < 2; tm++) {
            #pragma unroll
            for (int rr = 0; rr < 4; rr++) {
                int lrow = tm * 16 + kq * 4 + rr;
                size_t rb = (size_t)(bm + lrow) << 8;
                #pragma unroll
                for (int tn = 0; tn < 2; tn++) {
                    int col = wave * 32 + tn * 16 + mrow;
                    float v = acc[tm][tn][rr];
                    if (HASBIAS) v += biasReg[tn];
                    if (ADDC == 1) {
                        int u = col >> 3;
                        short s = *(const short*)((char*)At + (size_t)lrow * KP2 +
                                   ((u ^ (lrow & 7)) << 4) + ((col & 7) << 1));
                        v += bs2f(s);
                    } else if (ADDC == 2) {
                        v += addF[rb + col];
                    }
                    if (RELU) v = fmaxf(v, 0.f);
                    if (OUTF32) outF[rb + col] = v;
                    else        outB[rb + col] = f2b(v);
                }
            }
        }
        if (!more) break;
        if (ADDC == 1) __syncthreads();       // b4: epilogue LDS reads done
        tile = nxt;
    }
}

// W[K][256] f32 (rows Koff..Koff+K) -> Wt[256][Kp] bf16, zero pad k in [K,Kp)
__global__ __launch_bounds__(256) void convert_wt(
    const float* __restrict__ W, bf16* __restrict__ Wt, int K, int Koff, int Kp)
{
    int i = blockIdx.x * 256 + threadIdx.x;
    if (i >= 256 * Kp) return;
    int n = i / Kp, k = i - n * Kp;
    Wt[i] = (k < K) ? f2b(W[(size_t)(k + Koff) * 256 + n]) : f2b(0.f);
}

// amsg[a, c8..c8+8) = sum_k relu(msg[a2b[a,k], c8..c8+8)) ; 16B vector loads
__global__ __launch_bounds__(256) void gather_sum8(
    const bf16* __restrict__ msg, const int* __restrict__ a2b,
    bf16* __restrict__ amsg, int A)
{
    int idx = blockIdx.x * 256 + threadIdx.x;
    if (idx >= A * 32) return;
    int a  = idx >> 5;
    int c8 = (idx & 31) * 8;
    const int* nb = a2b + (size_t)a * 6;
    float s[8] = {};
    #pragma unroll
    for (int k = 0; k < 6; k++) {
        const short8 v = *(const short8*)(msg + ((size_t)nb[k] << 8) + c8);
        #pragma unroll
        for (int e = 0; e < 8; e++) s[e] += fmaxf(bs2f(v[e]), 0.f);
    }
    short8 o;
    #pragma unroll
    for (int e = 0; e < 8; e++) o[e] = f2bs(s[e]);
    *(short8*)(amsg + ((size_t)a << 8) + c8) = o;
}

// =============================== MLP (hi/lo) ===============================
#define K3 1536   // 3 * 512

// W[K][N] f32 -> W'[N][K3] bf16 planes [Wh | Wh | Wl], zero-padded k>=K
__global__ __launch_bounds__(256) void conv_w3(
    const float* __restrict__ W, bf16* __restrict__ Wp, int K, int N)
{
    int idx = blockIdx.x * 256 + threadIdx.x;
    if (idx >= N * 512) return;
    int n = idx >> 9, k = idx & 511;
    float w = (k < K) ? W[(size_t)k * N + n] : 0.f;
    bf16 hi = f2b(w);
    bf16 lo = f2b(w - b2f(hi));
    size_t base = (size_t)n * K3;
    Wp[base + k] = hi;
    Wp[base + 512 + k] = hi;
    Wp[base + 1024 + k] = lo;
}

// mol_features -> A1' planes at k in [256,512)  ([Ah | Al | Ah])
__global__ __launch_bounds__(256) void conv_feat(
    const float* __restrict__ mf, bf16* __restrict__ A1p)
{
    int idx = blockIdx.x * 256 + threadIdx.x;   // 4096*256
    int m = idx >> 8, j = idx & 255;
    float v = (j < 200) ? mf[(size_t)m * 200 + j] : 0.f;
    bf16 hi = f2b(v);
    bf16 lo = f2b(v - b2f(hi));
    size_t base = (size_t)m * K3 + 256;
    A1p[base + j] = hi;
    A1p[base + 512 + j] = lo;
    A1p[base + 1024 + j] = hi;
}

// per-molecule mean -> A1' planes at k in [0,256)
__global__ __launch_bounds__(256) void segment_mean3(
    const bf16* __restrict__ ah, const int* __restrict__ atom2mol,
    int A, bf16* __restrict__ A1p)
{
    int m = blockIdx.x;
    int h = threadIdx.x;
    int lo_ = 0, hi_ = A;
    while (lo_ < hi_) { int mid = (lo_ + hi_) >> 1; if (atom2mol[mid] < m) lo_ = mid + 1; else hi_ = mid; }
    int start = lo_;
    hi_ = A;
    while (lo_ < hi_) { int mid = (lo_ + hi_) >> 1; if (atom2mol[mid] <= m) lo_ = mid + 1; else hi_ = mid; }
    int end = lo_;
    float s = 0.f;
    for (int a = start; a < end; a++) s += b2f(ah[(size_t)a * 256 + h]);
    float mean = s / fmaxf((float)(end - start), 1.f);
    bf16 hi = f2b(mean);
    bf16 lo = f2b(mean - b2f(hi));
    size_t base = (size_t)m * K3;
    A1p[base + h] = hi;
    A1p[base + 512 + h] = lo;
    A1p[base + 1024 + h] = hi;
}

// bf16 MFMA GEMM over K3=1536: C = relu(A' @ W'^T + bias).
// 64x64 tile, BK=64, double-buffered LDS, 1 barrier per K-step.
// OUT3: emit hi/lo planes ([Ah|Al|Ah]) for the next GEMM; else f32 out.
template <bool OUT3>
__global__ __launch_bounds__(256, 2) void gemm3(
    int N,
    const bf16* __restrict__ Ap, const bf16* __restrict__ Wp,
    const float* __restrict__ bias,
    bf16* __restrict__ out3, float* __restrict__ outF)
{
    __shared__ bf16 As[2][64 * 64];   // 8 KiB each, XOR-swizzled 16B units
    __shared__ bf16 Bs[2][64 * 64];

    const int t = threadIdx.x;
    const int bm = blockIdx.x * 64, bn = blockIdx.y * 64;
    const int row = t >> 2, q = t & 3;          // staging: 4 thr/row, 2 units each
    const bf16* srcA = Ap + (size_t)(bm + row) * K3 + q * 16;
    const bf16* srcB = Wp + (size_t)(bn + row) * K3 + q * 16;

    short8 ra[2], rb[2];
    auto LOADT = [&](int t0) {
        #pragma unroll
        for (int u = 0; u < 2; u++) {
            ra[u] = *(const short8*)(srcA + t0 * 64 + u * 8);
            rb[u] = *(const short8*)(srcB + t0 * 64 + u * 8);
        }
    };
    auto WRITET = [&](int buf) {
        char* da = (char*)&As[buf][0] + row * 128;
        char* db = (char*)&Bs[buf][0] + row * 128;
        #pragma unroll
        for (int u = 0; u < 2; u++) {
            int g = q * 2 + u;
            *(short8*)(da + ((g ^ (row & 7)) << 4)) = ra[u];
            *(short8*)(db + ((g ^ (row & 7)) << 4)) = rb[u];
        }
    };

    const int wave = t >> 6, lane = t & 63;
    const int mrow = lane & 15, kq = lane >> 4;
    const int wm = (wave >> 1) * 32, wn = (wave & 1) * 32;

    f32x4 acc[2][2] = {};
    LOADT(0);
    WRITET(0);

    for (int t0 = 0; t0 < K3 / 64; t0++) {
        const int cur = t0 & 1;
        __syncthreads();                       // buf[cur] ready; prev reads done
        if (t0 + 1 < K3 / 64) LOADT(t0 + 1);
        #pragma unroll
        for (int ks = 0; ks < 2; ks++) {
            short8 af[2], bfr[2];
            #pragma unroll
            for (int i = 0; i < 2; i++) {
                int ar = wm + i * 16 + mrow;
                af[i] = *(const short8*)((char*)&As[cur][0] + ar * 128 +
                          (((ks * 4 + kq) ^ (ar & 7)) << 4));
            }
            #pragma unroll
            for (int jx = 0; jx < 2; jx++) {
                int br = wn + jx * 16 + mrow;
                bfr[jx] = *(const short8*)((char*)&Bs[cur][0] + br * 128 +
                          (((ks * 4 + kq) ^ (br & 7)) << 4));
            }
            #pragma unroll
            for (int i = 0; i < 2; i++)
                #pragma unroll
                for (int jx = 0; jx < 2; jx++)
                    acc[i][jx] = __builtin_amdgcn_mfma_f32_16x16x32_bf16(
                        af[i], bfr[jx], acc[i][jx], 0, 0, 0);
        }
        if (t0 + 1 < K3 / 64) WRITET(cur ^ 1);  // other buffer: no race
    }

    #pragma unroll
    for (int i = 0; i < 2; i++) {
        #pragma unroll
        for (int r = 0; r < 4; r++) {
            int grow = bm + wm + i * 16 + kq * 4 + r;
            #pragma unroll
            for (int jx = 0; jx < 2; jx++) {
                int gcol = bn + wn + jx * 16 + mrow;
                float v = acc[i][jx][r] + bias[gcol];
                v = fmaxf(v, 0.f);
                if (OUT3) {
                    bf16 hi = f2b(v);
                    bf16 lo = f2b(v - b2f(hi));
                    size_t base = (size_t)grow * K3;
                    out3[base + gcol] = hi;
                    out3[base + 512 + gcol] = lo;
                    out3[base + 1024 + gcol] = hi;
                } else {
                    outF[(size_t)grow * N + gcol] = v;
                }
            }
        }
    }
}

extern "C" void kernel_launch(void* const* d_in, const int* in_sizes, int n_in,
                              void* d_out, int out_size, void* d_ws, size_t ws_size,
                              hipStream_t stream)
{
    const float* f_atoms  = (const float*)d_in[0];
    const float* f_bonds  = (const float*)d_in[1];
    const int*   a2b      = (const int*)d_in[2];
    const int*   b2a      = (const int*)d_in[3];
    const int*   b2revb   = (const int*)d_in[4];
    const int*   atom2mol = (const int*)d_in[5];
    const float* mol_feat = (const float*)d_in[6];
    const float* W_i      = (const float*)d_in[7];
    const float* W_h      = (const float*)d_in[8];
    const float* W_o_w    = (const float*)d_in[9];
    const float* W_o_b    = (const float*)d_in[10];
    const float* W1       = (const float*)d_in[11];
    const float* b1       = (const float*)d_in[12];
    const float* W2       = (const float*)d_in[13];
    const float* b2       = (const float*)d_in[14];

    const int A  = 100000, B = 200000, H = 256;
    const int AF = 133, BF = 147;
    const int NM = 4096, FH = 512, EH = 256;
    const int KpS = 192;
    const int KpH = 256;

    char* ws = (char*)d_ws;
    bf16* buf0 = (bf16*)ws;  ws += (size_t)B * H * sizeof(bf16);     // 102.4 MB
    bf16* buf1 = (bf16*)ws;  ws += (size_t)B * H * sizeof(bf16);     // 102.4 MB (also f32 fbuf)
    bf16* amsg = (bf16*)ws;  ws += (size_t)A * H * sizeof(bf16);     //  51.2 MB
    bf16* WtI  = (bf16*)ws;  ws += (size_t)256 * KpS * sizeof(bf16);
    bf16* WtH  = (bf16*)ws;  ws += (size_t)256 * KpH * sizeof(bf16);
    bf16* WtO1 = (bf16*)ws;  ws += (size_t)256 * KpS * sizeof(bf16);
    bf16* WtO2 = (bf16*)ws;  ws += (size_t)256 * KpH * sizeof(bf16);
    bf16* W1p  = (bf16*)ws;  ws += (size_t)FH * K3 * sizeof(bf16);   // 1.57 MB
    bf16* W2p  = (bf16*)ws;  ws += (size_t)EH * K3 * sizeof(bf16);   // 0.79 MB
    float* fbuf = (float*)buf1;            // A*256*4 B == B*256*2 B exactly
    bf16* A1p = buf0;                      // overlay: buf0 free after step 3
    bf16* A2p = buf0 + (size_t)NM * K3;    // 12.6 MB each, well within buf0

    dim3 blk(256), blkG(512);
    const int ntB = B / TR;                   // 6250
    const int ntA = A / TR;                   // 3125
    const int gsG = (A * 32 + 255) / 256;     // 12500

    // 0. weight conversions
    convert_wt<<<dim3((256 * KpS + 255) / 256), blk, 0, stream>>>(W_i,   WtI,  BF,  0,  KpS);
    convert_wt<<<dim3((256 * KpH + 255) / 256), blk, 0, stream>>>(W_h,   WtH,  H,   0,  KpH);
    convert_wt<<<dim3((256 * KpS + 255) / 256), blk, 0, stream>>>(W_o_w, WtO1, AF,  0,  KpS);
    convert_wt<<<dim3((256 * KpH + 255) / 256), blk, 0, stream>>>(W_o_w, WtO2, H,   AF, KpH);
    conv_w3<<<dim3((FH * 512 + 255) / 256), blk, 0, stream>>>(W1, W1p, H + 200, FH);
    conv_w3<<<dim3((EH * 512 + 255) / 256), blk, 0, stream>>>(W2, W2p, FH, EH);

    // 1. buf0 = f_bonds @ W_i  (pre-relu)
    gemm_wres<192, 0, false, 0, false, false><<<dim3(GRID), blkG, 0, stream>>>(
        B, ntB, BF, f_bonds, nullptr, nullptr, nullptr, nullptr,
        WtI, nullptr, nullptr, nullptr, buf0, nullptr);

    // 2a. iter 1
    gather_sum8<<<dim3(gsG), blk, 0, stream>>>(buf0, a2b, amsg, A);
    gemm_wres<256, 1, true, 1, false, false><<<dim3(GRID), blkG, 0, stream>>>(
        B, ntB, H, nullptr, amsg, buf0, b2a, b2revb,
        WtH, nullptr, buf0, nullptr, buf1, nullptr);

    // 2b. iter 2 (in-place into buf0)
    gather_sum8<<<dim3(gsG), blk, 0, stream>>>(buf1, a2b, amsg, A);
    gemm_wres<256, 1, true, 1, false, false><<<dim3(GRID), blkG, 0, stream>>>(
        B, ntB, H, nullptr, amsg, buf1, b2a, b2revb,
        WtH, nullptr, buf0, nullptr, buf0, nullptr);

    // 3. final neighbor sum (last use of buf0 as message buffer)
    gather_sum8<<<dim3(gsG), blk, 0, stream>>>(buf0, a2b, amsg, A);

    // A1' feature part (buf0 region now free)
    conv_feat<<<dim3(NM), blk, 0, stream>>>(mol_feat, A1p);

    // 4a. fbuf = f_atoms @ W_o[0:133]  (f32 partials)
    gemm_wres<192, 0, false, 0, false, true><<<dim3(GRID), blkG, 0, stream>>>(
        A, ntA, AF, f_atoms, nullptr, nullptr, nullptr, nullptr,
        WtO1, nullptr, nullptr, nullptr, nullptr, fbuf);

    // 4b. amsg = relu(fbuf + amsg @ W_o[133:] + b)   (in-place over amsg)
    gemm_wres<256, 2, true, 2, true, false><<<dim3(GRID), blkG, 0, stream>>>(
        A, ntA, H, nullptr, amsg, nullptr, nullptr, nullptr,
        WtO2, W_o_b, nullptr, fbuf, amsg, nullptr);

    // 5. per-molecule mean -> A1' planes
    segment_mean3<<<dim3(NM), blk, 0, stream>>>(amsg, atom2mol, A, A1p);

    // 6. A2' = relu(A1' @ W1' + b1)   (hi/lo planes)
    gemm3<true><<<dim3(NM / 64, FH / 64), blk, 0, stream>>>(
        FH, A1p, W1p, b1, A2p, nullptr);

    // 7. out = relu(A2' @ W2' + b2)
    gemm3<false><<<dim3(NM / 64, EH / 64), blk, 0, stream>>>(
        EH, A2p, W2p, b2, nullptr, (float*)d_out);
}